// Round 3
// baseline (273.970 us; speedup 1.0000x reference)
//
#include <hip/hip_runtime.h>
#include <math.h>

// Shapes: B=128, S=192, N=32, PREC_DIM=2, E=64, H=4, D=16, FF=256, M=24576.
namespace {

constexpr int S_  = 192;
constexpr int TPW = 8;   // tokens per wave
constexpr int WVB = 4;   // waves per block; 32 tokens/block; grid = 768

// All LDS buffers are per-wave: cross-lane visibility within a wave only
// needs the LDS queue drained (in-order per-wave LDS processing).
__device__ __forceinline__ void wave_fence() {
  asm volatile("s_waitcnt lgkmcnt(0)" ::: "memory");
}

__launch_bounds__(256, 3)
__global__ void prec_fused(
    const float* __restrict__ prec,  const int*   __restrict__ tmask,
    const float* __restrict__ We,    const float* __restrict__ be,
    const float* __restrict__ Wq,    const float* __restrict__ Wk,
    const float* __restrict__ Wv,    const float* __restrict__ Wo,
    const float* __restrict__ bo,    const float* __restrict__ g1,
    const float* __restrict__ bb1,   const float* __restrict__ W1,
    const float* __restrict__ b1,    const float* __restrict__ W2,
    const float* __restrict__ b2,    const float* __restrict__ g2,
    const float* __restrict__ bb2,   float* __restrict__ out)
{
  __shared__ __align__(16) float scratch[WVB][2048];     // trans[32][64] / h1[8][256]
  __shared__ __align__(16) float sxoh[WVB][TPW][64];     // oh, then x
  __shared__ __align__(16) float sqrow[WVB][64];         // staged q row (pv[nstar])
  __shared__ __align__(16) float sqhv[WVB][64];          // qh

  const int tid  = threadIdx.x;
  const int wv   = tid >> 6;
  const int lane = tid & 63;
  const int u    = lane >> 5;   // feature half
  const int n    = lane & 31;   // precedence slot
  const int tokbase = (blockIdx.x * WVB + wv) * TPW;
  const int bidx0 = tokbase / S_;              // batch constant per wave (192 % 8 == 0)
  const int srow0 = tokbase - bidx0 * S_;

  float* __restrict__ trans = scratch[wv];
  float* __restrict__ sqw   = sqrow[wv];
  float* __restrict__ sqhw  = sqhv[wv];

  const bool masked = (tmask[bidx0 * 32 + n] == 0);   // token-invariant per wave

  // per-lane Wq column, token-invariant: wqr[dp] = Wq[dp][lane&15]
  float wqr[16];
  {
    const int col = lane & 15;
    #pragma unroll
    for (int dp = 0; dp < 16; ++dp) wqr[dp] = Wq[dp * 16 + col];
  }

  // ================= Phase A: attention, one token per wave per pass =================
  #pragma unroll 1
  for (int p = 0; p < TPW; ++p) {
    const int m     = tokbase + p;
    const int nstar = (srow0 + p) & 31;

    const float2 pin = *(const float2*)(prec + (size_t)m * 64 + n * 2);

    // pv row n in two 16-reg chunks: pva = features u*32+[0..15], pvb = +[16..31]
    float pva[16], pvb[16];
    {
      const float* w0p = We + u * 32;
      const float* w1p = We + 64 + u * 32;
      const float* bep = be + u * 32;
      #pragma unroll
      for (int j4 = 0; j4 < 4; ++j4) {
        const float4 a0 = *(const float4*)(w0p + j4 * 4);
        const float4 a1 = *(const float4*)(w1p + j4 * 4);
        const float4 ab = *(const float4*)(bep + j4 * 4);
        pva[j4*4+0] = fmaf(pin.x, a0.x, fmaf(pin.y, a1.x, ab.x));
        pva[j4*4+1] = fmaf(pin.x, a0.y, fmaf(pin.y, a1.y, ab.y));
        pva[j4*4+2] = fmaf(pin.x, a0.z, fmaf(pin.y, a1.z, ab.z));
        pva[j4*4+3] = fmaf(pin.x, a0.w, fmaf(pin.y, a1.w, ab.w));
      }
      #pragma unroll
      for (int j4 = 0; j4 < 4; ++j4) {
        const float4 a0 = *(const float4*)(w0p + 16 + j4 * 4);
        const float4 a1 = *(const float4*)(w1p + 16 + j4 * 4);
        const float4 ab = *(const float4*)(bep + 16 + j4 * 4);
        pvb[j4*4+0] = fmaf(pin.x, a0.x, fmaf(pin.y, a1.x, ab.x));
        pvb[j4*4+1] = fmaf(pin.x, a0.y, fmaf(pin.y, a1.y, ab.y));
        pvb[j4*4+2] = fmaf(pin.x, a0.z, fmaf(pin.y, a1.z, ab.z));
        pvb[j4*4+3] = fmaf(pin.x, a0.w, fmaf(pin.y, a1.w, ab.w));
      }
    }

    // stage q row (the two lanes holding row nstar write it)
    if (n == nstar) {
      #pragma unroll
      for (int j4 = 0; j4 < 4; ++j4) {
        float4 t0; t0.x = pva[j4*4]; t0.y = pva[j4*4+1]; t0.z = pva[j4*4+2]; t0.w = pva[j4*4+3];
        *(float4*)&sqw[u*32 + j4*4] = t0;
        float4 t1; t1.x = pvb[j4*4]; t1.y = pvb[j4*4+1]; t1.z = pvb[j4*4+2]; t1.w = pvb[j4*4+3];
        *(float4*)&sqw[u*32 + 16 + j4*4] = t1;
      }
    }

    // kh/vh: register-local, weights via uniform (scalar-cache) loads — no LDS
    float khr[32], vhr[32];
    #pragma unroll
    for (int c = 0; c < 16; ++c) {
      const float wk  = Wk[c];
      const float wvv = Wv[c];
      khr[c]      = pva[0] * wk;
      vhr[c]      = pva[0] * wvv;
      khr[16 + c] = pvb[0] * wk;
      vhr[16 + c] = pvb[0] * wvv;
    }
    #pragma unroll
    for (int dp = 1; dp < 16; ++dp) {
      #pragma unroll
      for (int c = 0; c < 16; ++c) {
        const float wk  = Wk[dp * 16 + c];
        const float wvv = Wv[dp * 16 + c];
        khr[c]      = fmaf(pva[dp], wk,  khr[c]);
        vhr[c]      = fmaf(pva[dp], wvv, vhr[c]);
        khr[16 + c] = fmaf(pvb[dp], wk,  khr[16 + c]);
        vhr[16 + c] = fmaf(pvb[dp], wvv, vhr[16 + c]);
      }
    }
    wave_fence();   // q row visible

    // qh[lane] = sum_dp q[(lane>>4)*16+dp] * Wq[dp][lane&15]
    const int hg = lane >> 4;
    float qh = 0.f;
    #pragma unroll
    for (int k = 0; k < 4; ++k) {
      const float4 q4 = *(const float4*)&sqw[hg * 16 + k * 4];
      qh = fmaf(q4.x, wqr[k*4+0], qh);
      qh = fmaf(q4.y, wqr[k*4+1], qh);
      qh = fmaf(q4.z, wqr[k*4+2], qh);
      qh = fmaf(q4.w, wqr[k*4+3], qh);
    }
    sqhw[lane] = qh;
    wave_fence();   // qh visible

    // energy for this lane's two local heads (2u, 2u+1)
    float en0 = 0.f, en1 = 0.f;
    #pragma unroll
    for (int k = 0; k < 4; ++k) {
      const float4 q4 = *(const float4*)&sqhw[u*32 + k*4];
      en0 = fmaf(q4.x, khr[k*4+0], en0);
      en0 = fmaf(q4.y, khr[k*4+1], en0);
      en0 = fmaf(q4.z, khr[k*4+2], en0);
      en0 = fmaf(q4.w, khr[k*4+3], en0);
    }
    #pragma unroll
    for (int k = 0; k < 4; ++k) {
      const float4 q4 = *(const float4*)&sqhw[u*32 + 16 + k*4];
      en1 = fmaf(q4.x, khr[16 + k*4+0], en1);
      en1 = fmaf(q4.y, khr[16 + k*4+1], en1);
      en1 = fmaf(q4.z, khr[16 + k*4+2], en1);
      en1 = fmaf(q4.w, khr[16 + k*4+3], en1);
    }

    // mask, scale 1/sqrt(E)=0.125, softmax over n
    en0 = masked ? -1e20f : en0;
    en1 = masked ? -1e20f : en1;
    en0 *= 0.125f; en1 *= 0.125f;
    float mx0 = en0, mx1 = en1;
    #pragma unroll
    for (int o = 1; o < 32; o <<= 1) {
      mx0 = fmaxf(mx0, __shfl_xor(mx0, o, 64));
      mx1 = fmaxf(mx1, __shfl_xor(mx1, o, 64));
    }
    const float pe0 = __expf(en0 - mx0), pe1 = __expf(en1 - mx1);
    float s0 = pe0, s1 = pe1;
    #pragma unroll
    for (int o = 1; o < 32; o <<= 1) {
      s0 += __shfl_xor(s0, o, 64);
      s1 += __shfl_xor(s1, o, 64);
    }
    const float w0 = pe0 / s0, w1 = pe1 / s1;

    // PV: weighted rows -> xor-swizzled transpose tile
    const int sw = (n & 7) << 2;
    #pragma unroll
    for (int j4 = 0; j4 < 8; ++j4) {
      const float ww = (j4 < 4) ? w0 : w1;
      float4 t;
      t.x = ww * vhr[j4*4+0]; t.y = ww * vhr[j4*4+1];
      t.z = ww * vhr[j4*4+2]; t.w = ww * vhr[j4*4+3];
      *(float4*)&trans[n * 64 + ((u * 32 + j4 * 4) ^ sw)] = t;
    }
    wave_fence();
    float oh = 0.f;
    #pragma unroll
    for (int r = 0; r < 32; ++r)
      oh += trans[r * 64 + (lane ^ ((r & 7) << 2))];
    sxoh[wv][p][lane] = oh;
    wave_fence();   // also protects trans/sqw reuse next pass
  }

  // ================= Phase B: ao + LN1 + FF + LN2 =================
  // residual q recomputed
  const float we0l = We[lane], we1l = We[64 + lane], bel = be[lane];
  float qv[TPW];
  #pragma unroll
  for (int t = 0; t < TPW; ++t) {
    const int m  = tokbase + t;
    const int ns = (srow0 + t) & 31;
    const float q0 = prec[(size_t)m * 64 + ns * 2];
    const float q1 = prec[(size_t)m * 64 + ns * 2 + 1];
    qv[t] = fmaf(q0, we0l, fmaf(q1, we1l, bel));
  }

  // ao = oh @ Wo + bo
  float ao[TPW];
  {
    const float bol = bo[lane];
    #pragma unroll
    for (int t = 0; t < TPW; ++t) ao[t] = bol;
  }
  #pragma unroll 4
  for (int e4 = 0; e4 < 16; ++e4) {
    const float w0_ = Wo[(e4*4+0)*64 + lane];
    const float w1_ = Wo[(e4*4+1)*64 + lane];
    const float w2_ = Wo[(e4*4+2)*64 + lane];
    const float w3_ = Wo[(e4*4+3)*64 + lane];
    #pragma unroll
    for (int t = 0; t < TPW; ++t) {
      const float4 o4 = *(const float4*)&sxoh[wv][t][e4*4];
      ao[t] = fmaf(o4.x, w0_, ao[t]);
      ao[t] = fmaf(o4.y, w1_, ao[t]);
      ao[t] = fmaf(o4.z, w2_, ao[t]);
      ao[t] = fmaf(o4.w, w3_, ao[t]);
    }
  }
  wave_fence();

  // LN1 (one-pass), x -> sxoh
  {
    const float g1l = g1[lane], b1l_ = bb1[lane];
    #pragma unroll
    for (int t = 0; t < TPW; ++t) {
      const float v = ao[t] + qv[t];
      float sm = v, s2 = v * v;
      #pragma unroll
      for (int o = 1; o < 64; o <<= 1) {
        sm += __shfl_xor(sm, o, 64);
        s2 += __shfl_xor(s2, o, 64);
      }
      const float mu  = sm * (1.f/64.f);
      const float var = s2 * (1.f/64.f) - mu * mu;
      const float rs  = rsqrtf(var + 1e-5f);
      sxoh[wv][t][lane] = (v - mu) * rs * g1l + b1l_;
    }
  }
  wave_fence();

  // h1 = relu(x @ W1 + b1); lane owns cols lane+64k
  float hacc[TPW][4];
  {
    #pragma unroll
    for (int k = 0; k < 4; ++k) {
      const float bk = b1[lane + 64*k];
      #pragma unroll
      for (int t = 0; t < TPW; ++t) hacc[t][k] = bk;
    }
  }
  #pragma unroll 4
  for (int e4 = 0; e4 < 16; ++e4) {
    float wr[4][4];
    #pragma unroll
    for (int kk = 0; kk < 4; ++kk) {
      #pragma unroll
      for (int k = 0; k < 4; ++k)
        wr[kk][k] = W1[(e4*4+kk)*256 + lane + 64*k];
    }
    #pragma unroll
    for (int t = 0; t < TPW; ++t) {
      const float4 xv = *(const float4*)&sxoh[wv][t][e4*4];
      #pragma unroll
      for (int k = 0; k < 4; ++k) {
        hacc[t][k] = fmaf(xv.x, wr[0][k], hacc[t][k]);
        hacc[t][k] = fmaf(xv.y, wr[1][k], hacc[t][k]);
        hacc[t][k] = fmaf(xv.z, wr[2][k], hacc[t][k]);
        hacc[t][k] = fmaf(xv.w, wr[3][k], hacc[t][k]);
      }
    }
  }
  float* __restrict__ h1buf = scratch[wv];   // overlay (trans dead)
  #pragma unroll
  for (int t = 0; t < TPW; ++t) {
    #pragma unroll
    for (int k = 0; k < 4; ++k)
      h1buf[t*256 + lane + 64*k] = fmaxf(hacc[t][k], 0.f);
  }
  wave_fence();

  // ff2 = h1 @ W2 + b2 in (4 tokens x 2 cols)/lane layout
  const int tg = lane >> 5;          // token group: t = tg*4 + i
  const int e0 = (lane & 31) * 2;    // output cols e0, e0+1
  float f2a[4][2];
  {
    const float2 b2v = *(const float2*)(b2 + e0);
    #pragma unroll
    for (int i = 0; i < 4; ++i) { f2a[i][0] = b2v.x; f2a[i][1] = b2v.y; }
  }
  const float* __restrict__ hb = h1buf + tg * 4 * 256;
  #pragma unroll 8
  for (int f4 = 0; f4 < 64; ++f4) {
    float4 hv[4];
    #pragma unroll
    for (int i = 0; i < 4; ++i)
      hv[i] = *(const float4*)(hb + i*256 + f4*4);
    float2 w2r[4];
    #pragma unroll
    for (int ff = 0; ff < 4; ++ff)
      w2r[ff] = *(const float2*)(W2 + (f4*4+ff)*64 + e0);
    #pragma unroll
    for (int i = 0; i < 4; ++i) {
      f2a[i][0] = fmaf(hv[i].x, w2r[0].x, f2a[i][0]);
      f2a[i][1] = fmaf(hv[i].x, w2r[0].y, f2a[i][1]);
      f2a[i][0] = fmaf(hv[i].y, w2r[1].x, f2a[i][0]);
      f2a[i][1] = fmaf(hv[i].y, w2r[1].y, f2a[i][1]);
      f2a[i][0] = fmaf(hv[i].z, w2r[2].x, f2a[i][0]);
      f2a[i][1] = fmaf(hv[i].z, w2r[2].y, f2a[i][1]);
      f2a[i][0] = fmaf(hv[i].w, w2r[3].x, f2a[i][0]);
      f2a[i][1] = fmaf(hv[i].w, w2r[3].y, f2a[i][1]);
    }
  }

  // LN2 + store (reduction over 32-lane half: all lanes in a half share tg)
  {
    const float2 g2v  = *(const float2*)(g2 + e0);
    const float2 bb2v = *(const float2*)(bb2 + e0);
    #pragma unroll
    for (int i = 0; i < 4; ++i) {
      const int t = tg * 4 + i;
      const float2 xv = *(const float2*)&sxoh[wv][t][e0];
      const float v0 = f2a[i][0] + xv.x;
      const float v1 = f2a[i][1] + xv.y;
      float sm = v0 + v1, s2 = v0*v0 + v1*v1;
      #pragma unroll
      for (int o = 1; o < 32; o <<= 1) {
        sm += __shfl_xor(sm, o, 64);
        s2 += __shfl_xor(s2, o, 64);
      }
      const float mu  = sm * (1.f/64.f);
      const float var = s2 * (1.f/64.f) - mu * mu;
      const float rs  = rsqrtf(var + 1e-5f);
      float2 o2;
      o2.x = (v0 - mu) * rs * g2v.x + bb2v.x;
      o2.y = (v1 - mu) * rs * g2v.y + bb2v.y;
      *(float2*)(out + (size_t)(tokbase + t) * 64 + e0) = o2;
    }
  }
}

} // namespace

extern "C" void kernel_launch(void* const* d_in, const int* in_sizes, int n_in,
                              void* d_out, int out_size, void* d_ws, size_t ws_size,
                              hipStream_t stream) {
  (void)in_sizes; (void)n_in; (void)d_ws; (void)ws_size; (void)out_size;
  const float* prec = (const float*)d_in[0];
  const int*   tm   = (const int*)  d_in[1];
  const float* We   = (const float*)d_in[2];
  const float* be   = (const float*)d_in[3];
  const float* Wq   = (const float*)d_in[4];
  const float* Wk   = (const float*)d_in[5];
  const float* Wv   = (const float*)d_in[6];
  const float* Wo   = (const float*)d_in[7];
  const float* bo   = (const float*)d_in[8];
  const float* g1   = (const float*)d_in[9];
  const float* bb1  = (const float*)d_in[10];
  const float* W1   = (const float*)d_in[11];
  const float* b1   = (const float*)d_in[12];
  const float* W2   = (const float*)d_in[13];
  const float* b2   = (const float*)d_in[14];
  const float* g2   = (const float*)d_in[15];
  const float* bb2  = (const float*)d_in[16];

  dim3 grid(768), block(256);
  hipLaunchKernelGGL(prec_fused, grid, block, 0, stream,
                     prec, tm, We, be, Wq, Wk, Wv, Wo, bo, g1, bb1,
                     W1, b1, W2, b2, g2, bb2, (float*)d_out);
}

// Round 4
// 143.537 us; speedup vs baseline: 1.9087x; 1.9087x over previous
//
#include <hip/hip_runtime.h>
#include <math.h>

// Shapes: B=128, S=192, N=32, PREC_DIM=2, E=64, H=4, D=16, FF=256, M=24576.
//
// Key algebra: pv_n = Ue^T pvec_n with pvec=(x,y,1), Ue=[We0;We1;be] (3x64).
// energy[h][n] = qvec^T M_h pvec_n,  M_h = (Ue_h Wq)(Ue_h Wk)^T  (3x3/head)
// ao[e] = sum_h ctxvec_h . G_h[:,e], G_h = (Ue_h Wv) Wo_h (3x64/head),
// ctxvec_h = sum_n attn[h][n]*(x_n,y_n,1)  (3 scalars/head).
namespace {

constexpr int S_  = 192;
constexpr int TPW = 8;   // tokens per wave
constexpr int WVB = 4;   // waves per block; 32 tokens/block; grid = 768

// All LDS buffers are per-wave: visibility within a wave only needs the
// LDS queue drained (in-order per-wave LDS processing).
__device__ __forceinline__ void wave_fence() {
  asm volatile("s_waitcnt lgkmcnt(0)" ::: "memory");
}

__launch_bounds__(256, 4)
__global__ void prec_fused(
    const float* __restrict__ prec,  const int*   __restrict__ tmask,
    const float* __restrict__ We,    const float* __restrict__ be,
    const float* __restrict__ Wq,    const float* __restrict__ Wk,
    const float* __restrict__ Wv,    const float* __restrict__ Wo,
    const float* __restrict__ bo,    const float* __restrict__ g1,
    const float* __restrict__ bb1,   const float* __restrict__ W1,
    const float* __restrict__ b1,    const float* __restrict__ W2,
    const float* __restrict__ b2,    const float* __restrict__ g2,
    const float* __restrict__ bb2,   float* __restrict__ out)
{
  // per-wave scratch: prologue staging, then h1[8][256] in phase B
  __shared__ __align__(16) float scratch[WVB][2048];
  // per-wave: x[8][64] (LN1 output)
  __shared__ __align__(16) float sxoh[WVB][TPW][64];

  const int tid  = threadIdx.x;
  const int wv   = tid >> 6;
  const int lane = tid & 63;
  const int u    = lane >> 5;   // half index
  const int n    = lane & 31;   // precedence slot (phase A row)
  const int tokbase = (blockIdx.x * WVB + wv) * TPW;
  const int bidx0 = tokbase / S_;              // batch constant per wave (192%8==0)
  const int srow0 = tokbase - bidx0 * S_;

  float* __restrict__ sc = scratch[wv];

  const bool masked = (tmask[bidx0 * 32 + n] == 0);

  // ---------------- Prologue: stage small weights (per-wave, redundant) ----------------
  // layout in sc (floats): 0:We0[64] 64:We1[64] 128:be[64] 192:Wq[256]
  //                        448:Wk[256] 704:Wv[256] 960:Ve[192] 1152:M[36]
  sc[lane]       = We[lane];
  sc[64 + lane]  = We[64 + lane];
  sc[128 + lane] = be[lane];
  #pragma unroll
  for (int i = 0; i < 4; ++i) {
    sc[192 + lane + 64*i] = Wq[lane + 64*i];
    sc[448 + lane + 64*i] = Wk[lane + 64*i];
    sc[704 + lane + 64*i] = Wv[lane + 64*i];
  }
  wave_fence();

  // Te/Ke/Ve rows: lane (h = lane>>4, c = lane&15) computes
  //   Te[a] = sum_dp Ue_a[h*16+dp] * Wq[dp*16+c]   (and Ke with Wk, Ve with Wv)
  {
    const int h = lane >> 4, c = lane & 15;
    float Te[3] = {0,0,0}, Ke[3] = {0,0,0}, Ve[3] = {0,0,0};
    #pragma unroll
    for (int dp = 0; dp < 16; ++dp) {
      const float u0 = sc[h*16 + dp];
      const float u1 = sc[64 + h*16 + dp];
      const float u2 = sc[128 + h*16 + dp];
      const float wq = sc[192 + dp*16 + c];
      const float wk = sc[448 + dp*16 + c];
      const float wvv = sc[704 + dp*16 + c];
      Te[0] = fmaf(u0, wq, Te[0]); Te[1] = fmaf(u1, wq, Te[1]); Te[2] = fmaf(u2, wq, Te[2]);
      Ke[0] = fmaf(u0, wk, Ke[0]); Ke[1] = fmaf(u1, wk, Ke[1]); Ke[2] = fmaf(u2, wk, Ke[2]);
      Ve[0] = fmaf(u0, wvv, Ve[0]); Ve[1] = fmaf(u1, wvv, Ve[1]); Ve[2] = fmaf(u2, wvv, Ve[2]);
    }
    // M_h[a][b] = sum_c Te[a]*Ke[b], reduce over the 16-lane group
    float Mp[9];
    #pragma unroll
    for (int a = 0; a < 3; ++a)
      #pragma unroll
      for (int b = 0; b < 3; ++b)
        Mp[a*3+b] = Te[a] * Ke[b];
    #pragma unroll
    for (int o = 1; o < 16; o <<= 1) {
      #pragma unroll
      for (int i = 0; i < 9; ++i) Mp[i] += __shfl_xor(Mp[i], o, 64);
    }
    #pragma unroll
    for (int a = 0; a < 3; ++a) sc[960 + (h*3 + a)*16 + c] = Ve[a];
    if (c == 0) {
      #pragma unroll
      for (int i = 0; i < 9; ++i) sc[1152 + h*9 + i] = Mp[i];
    }
  }
  wave_fence();

  // per-lane token-invariant registers
  float m0[9], m1[9];
  #pragma unroll
  for (int i = 0; i < 9; ++i) {
    m0[i] = sc[1152 + (2*u)*9 + i];
    m1[i] = sc[1152 + (2*u + 1)*9 + i];
  }
  // G rows for my output feature e=lane: own-half heads (2u,2u+1), other half
  float gO0[3] = {0,0,0}, gO1[3] = {0,0,0}, gT0[3] = {0,0,0}, gT1[3] = {0,0,0};
  {
    const int hoA = 2*u, hoB = 2*u + 1, htA = 2*(1 - u), htB = htA + 1;
    #pragma unroll
    for (int dp = 0; dp < 16; ++dp) {
      const float woA = Wo[(hoA*16 + dp)*64 + lane];
      const float woB = Wo[(hoB*16 + dp)*64 + lane];
      const float woC = Wo[(htA*16 + dp)*64 + lane];
      const float woD = Wo[(htB*16 + dp)*64 + lane];
      #pragma unroll
      for (int a = 0; a < 3; ++a) {
        gO0[a] = fmaf(sc[960 + (hoA*3 + a)*16 + dp], woA, gO0[a]);
        gO1[a] = fmaf(sc[960 + (hoB*3 + a)*16 + dp], woB, gO1[a]);
        gT0[a] = fmaf(sc[960 + (htA*3 + a)*16 + dp], woC, gT0[a]);
        gT1[a] = fmaf(sc[960 + (htB*3 + a)*16 + dp], woD, gT1[a]);
      }
    }
  }
  const float we0l = sc[lane], we1l = sc[64 + lane], bel = sc[128 + lane];
  const float bo_l = bo[lane], g1l = g1[lane], b1l_ = bb1[lane];
  wave_fence();   // done with sc until phase B reuses it

  // ================= Phase A: attention + ao + LN1, one token per pass =================
  #pragma unroll 1
  for (int p = 0; p < TPW; ++p) {
    const int m     = tokbase + p;
    const int nstar = (srow0 + p) & 31;

    const float qx = prec[(size_t)m * 64 + nstar * 2];
    const float qy = prec[(size_t)m * 64 + nstar * 2 + 1];
    const float2 pin = *(const float2*)(prec + (size_t)m * 64 + n * 2);

    // energy coefs: en = cA*x + cB*y + cC, c* = qvec^T M (per head)
    const float cA0 = fmaf(qy, m0[3], fmaf(qx, m0[0], m0[6]));
    const float cB0 = fmaf(qy, m0[4], fmaf(qx, m0[1], m0[7]));
    const float cC0 = fmaf(qy, m0[5], fmaf(qx, m0[2], m0[8]));
    const float cA1 = fmaf(qy, m1[3], fmaf(qx, m1[0], m1[6]));
    const float cB1 = fmaf(qy, m1[4], fmaf(qx, m1[1], m1[7]));
    const float cC1 = fmaf(qy, m1[5], fmaf(qx, m1[2], m1[8]));

    const float en0 = fmaf(pin.y, cB0, fmaf(pin.x, cA0, cC0)) * 0.125f;
    const float en1 = fmaf(pin.y, cB1, fmaf(pin.x, cA1, cC1)) * 0.125f;

    // softmax without max-subtract (energies are tiny; masked -> pe=0)
    const float pe0 = masked ? 0.f : __expf(en0);
    const float pe1 = masked ? 0.f : __expf(en1);
    float s0 = pe0, s1 = pe1;
    #pragma unroll
    for (int o = 1; o < 32; o <<= 1) {
      s0 += __shfl_xor(s0, o, 64);
      s1 += __shfl_xor(s1, o, 64);
    }
    const float w0 = (s0 > 0.f) ? pe0 / s0 : 0.03125f;   // all-masked -> uniform
    const float w1 = (s1 > 0.f) ? pe1 / s1 : 0.03125f;

    // ctxvec per head: (sum w*x, sum w*y, sum w) via 32-lane butterfly
    float r0 = w0 * pin.x, r1 = w0 * pin.y, r2 = w0;
    float r3 = w1 * pin.x, r4 = w1 * pin.y, r5 = w1;
    #pragma unroll
    for (int o = 1; o < 32; o <<= 1) {
      r0 += __shfl_xor(r0, o, 64); r1 += __shfl_xor(r1, o, 64);
      r2 += __shfl_xor(r2, o, 64); r3 += __shfl_xor(r3, o, 64);
      r4 += __shfl_xor(r4, o, 64); r5 += __shfl_xor(r5, o, 64);
    }
    // other half's two heads
    const float o0 = __shfl_xor(r0, 32, 64), o1 = __shfl_xor(r1, 32, 64);
    const float o2 = __shfl_xor(r2, 32, 64), o3 = __shfl_xor(r3, 32, 64);
    const float o4 = __shfl_xor(r4, 32, 64), o5 = __shfl_xor(r5, 32, 64);

    // ao[e] + bo + residual q[e]
    float v = bo_l;
    v = fmaf(r0, gO0[0], v); v = fmaf(r1, gO0[1], v); v = fmaf(r2, gO0[2], v);
    v = fmaf(r3, gO1[0], v); v = fmaf(r4, gO1[1], v); v = fmaf(r5, gO1[2], v);
    v = fmaf(o0, gT0[0], v); v = fmaf(o1, gT0[1], v); v = fmaf(o2, gT0[2], v);
    v = fmaf(o3, gT1[0], v); v = fmaf(o4, gT1[1], v); v = fmaf(o5, gT1[2], v);
    v += fmaf(qy, we1l, fmaf(qx, we0l, bel));

    // LN1 over 64 features
    float sm = v, s2 = v * v;
    #pragma unroll
    for (int o = 1; o < 64; o <<= 1) {
      sm += __shfl_xor(sm, o, 64);
      s2 += __shfl_xor(s2, o, 64);
    }
    const float mu  = sm * (1.f/64.f);
    const float var = s2 * (1.f/64.f) - mu * mu;
    const float rs  = rsqrtf(var + 1e-5f);
    sxoh[wv][p][lane] = (v - mu) * rs * g1l + b1l_;
  }
  wave_fence();

  // ================= Phase B: FF (h1, ff2) + LN2 =================
  // h1 = relu(x @ W1 + b1); lane owns cols lane+64k
  float hacc[TPW][4];
  #pragma unroll
  for (int k = 0; k < 4; ++k) {
    const float bk = b1[lane + 64*k];
    #pragma unroll
    for (int t = 0; t < TPW; ++t) hacc[t][k] = bk;
  }
  #pragma unroll 4
  for (int e4 = 0; e4 < 16; ++e4) {
    float wr[4][4];
    #pragma unroll
    for (int kk = 0; kk < 4; ++kk)
      #pragma unroll
      for (int k = 0; k < 4; ++k)
        wr[kk][k] = W1[(e4*4 + kk)*256 + lane + 64*k];
    #pragma unroll
    for (int t = 0; t < TPW; ++t) {
      const float4 xv = *(const float4*)&sxoh[wv][t][e4*4];
      #pragma unroll
      for (int k = 0; k < 4; ++k) {
        hacc[t][k] = fmaf(xv.x, wr[0][k], hacc[t][k]);
        hacc[t][k] = fmaf(xv.y, wr[1][k], hacc[t][k]);
        hacc[t][k] = fmaf(xv.z, wr[2][k], hacc[t][k]);
        hacc[t][k] = fmaf(xv.w, wr[3][k], hacc[t][k]);
      }
    }
  }
  float* __restrict__ h1buf = sc;   // overlay (prologue data dead)
  #pragma unroll
  for (int t = 0; t < TPW; ++t)
    #pragma unroll
    for (int k = 0; k < 4; ++k)
      h1buf[t*256 + lane + 64*k] = fmaxf(hacc[t][k], 0.f);
  wave_fence();

  // ff2 = h1 @ W2 + b2 in (4 tokens x 2 cols)/lane layout
  const int tg = lane >> 5;          // token group: t = tg*4 + i
  const int e0 = (lane & 31) * 2;    // output cols e0, e0+1
  float f2a[4][2];
  {
    const float2 b2v = *(const float2*)(b2 + e0);
    #pragma unroll
    for (int i = 0; i < 4; ++i) { f2a[i][0] = b2v.x; f2a[i][1] = b2v.y; }
  }
  const float* __restrict__ hb = h1buf + tg * 4 * 256;
  #pragma unroll 8
  for (int f4 = 0; f4 < 64; ++f4) {
    float4 hv[4];
    #pragma unroll
    for (int i = 0; i < 4; ++i)
      hv[i] = *(const float4*)(hb + i*256 + f4*4);
    float2 w2r[4];
    #pragma unroll
    for (int ff = 0; ff < 4; ++ff)
      w2r[ff] = *(const float2*)(W2 + (f4*4 + ff)*64 + e0);
    #pragma unroll
    for (int i = 0; i < 4; ++i) {
      f2a[i][0] = fmaf(hv[i].x, w2r[0].x, f2a[i][0]);
      f2a[i][1] = fmaf(hv[i].x, w2r[0].y, f2a[i][1]);
      f2a[i][0] = fmaf(hv[i].y, w2r[1].x, f2a[i][0]);
      f2a[i][1] = fmaf(hv[i].y, w2r[1].y, f2a[i][1]);
      f2a[i][0] = fmaf(hv[i].z, w2r[2].x, f2a[i][0]);
      f2a[i][1] = fmaf(hv[i].z, w2r[2].y, f2a[i][1]);
      f2a[i][0] = fmaf(hv[i].w, w2r[3].x, f2a[i][0]);
      f2a[i][1] = fmaf(hv[i].w, w2r[3].y, f2a[i][1]);
    }
  }

  // LN2 + store (reduction within 32-lane half; a half shares tg)
  {
    const float2 g2v  = *(const float2*)(g2 + e0);
    const float2 bb2v = *(const float2*)(bb2 + e0);
    #pragma unroll
    for (int i = 0; i < 4; ++i) {
      const int t = tg * 4 + i;
      const float2 xv = *(const float2*)&sxoh[wv][t][e0];
      const float v0 = f2a[i][0] + xv.x;
      const float v1 = f2a[i][1] + xv.y;
      float sm = v0 + v1, s2 = v0*v0 + v1*v1;
      #pragma unroll
      for (int o = 1; o < 32; o <<= 1) {
        sm += __shfl_xor(sm, o, 64);
        s2 += __shfl_xor(s2, o, 64);
      }
      const float mu  = sm * (1.f/64.f);
      const float var = s2 * (1.f/64.f) - mu * mu;
      const float rs  = rsqrtf(var + 1e-5f);
      float2 o2;
      o2.x = (v0 - mu) * rs * g2v.x + bb2v.x;
      o2.y = (v1 - mu) * rs * g2v.y + bb2v.y;
      *(float2*)(out + (size_t)(tokbase + t) * 64 + e0) = o2;
    }
  }
}

} // namespace

extern "C" void kernel_launch(void* const* d_in, const int* in_sizes, int n_in,
                              void* d_out, int out_size, void* d_ws, size_t ws_size,
                              hipStream_t stream) {
  (void)in_sizes; (void)n_in; (void)d_ws; (void)ws_size; (void)out_size;
  const float* prec = (const float*)d_in[0];
  const int*   tm   = (const int*)  d_in[1];
  const float* We   = (const float*)d_in[2];
  const float* be   = (const float*)d_in[3];
  const float* Wq   = (const float*)d_in[4];
  const float* Wk   = (const float*)d_in[5];
  const float* Wv   = (const float*)d_in[6];
  const float* Wo   = (const float*)d_in[7];
  const float* bo   = (const float*)d_in[8];
  const float* g1   = (const float*)d_in[9];
  const float* bb1  = (const float*)d_in[10];
  const float* W1   = (const float*)d_in[11];
  const float* b1   = (const float*)d_in[12];
  const float* W2   = (const float*)d_in[13];
  const float* b2   = (const float*)d_in[14];
  const float* g2   = (const float*)d_in[15];
  const float* bb2  = (const float*)d_in[16];

  dim3 grid(768), block(256);
  hipLaunchKernelGGL(prec_fused, grid, block, 0, stream,
                     prec, tm, We, be, Wq, Wk, Wv, Wo, bo, g1, bb1,
                     W1, b1, W2, b2, g2, bb2, (float*)d_out);
}